// Round 1
// baseline (22831.982 us; speedup 1.0000x reference)
//
#include <hip/hip_runtime.h>
#include <hip/hip_bf16.h>
#include <stdint.h>

// SSR-GRU (RK2 blend), 2 layers. S=512 B=128 I=256 H=512.
// Design: persistent per-layer kernel, 32 WGs x 256thr. Each WG owns 16 hidden
// cols (48 gh cols incl. 3 gates). Wh/Wx slices resident in LDS (XOR-swizzled).
// h broadcast via global bf16 ping-pong buffers + custom agent-scope barrier.
// Master h/f1/half state kept f32 in registers (no bf16 accumulation drift).

#define S_LEN 512
#define BATCH 128
#define HID   512
#define NWG   32
#define HC    16
#define THREADS 256

typedef __attribute__((ext_vector_type(8))) short short8;
typedef __attribute__((ext_vector_type(4))) float f32x4;

static __device__ __forceinline__ f32x4 mfma16(short8 a, short8 b, f32x4 c) {
  return __builtin_amdgcn_mfma_f32_16x16x32_bf16(a, b, c, 0, 0, 0);
}

static __device__ __forceinline__ unsigned short f2bf(float f) {
  union { float f; unsigned u; } v; v.f = f;
  unsigned r = (v.u + 0x7fffu + ((v.u >> 16) & 1u)) >> 16;
  return (unsigned short)r;
}

static __device__ __forceinline__ float sigmoidf_(float x) {
  x = fminf(fmaxf(x, -30.f), 30.f);
  return 1.0f / (1.0f + __expf(-x));
}
static __device__ __forceinline__ float tanhf_(float x) {
  x = fminf(fmaxf(x, -15.f), 15.f);
  float e = __expf(2.f * x);
  return (e - 1.f) / (e + 1.f);
}

// ---------------- f32 -> bf16 conversion ----------------
__global__ void cvt_bf16_kernel(const float* __restrict__ src,
                                unsigned short* __restrict__ dst, int n) {
  int i = (blockIdx.x * blockDim.x + threadIdx.x) * 4;
  if (i + 3 < n) {
    float4 v = *(const float4*)(src + i);
    unsigned short o0 = f2bf(v.x), o1 = f2bf(v.y), o2 = f2bf(v.z), o3 = f2bf(v.w);
    unsigned long long pack = (unsigned long long)o0 | ((unsigned long long)o1 << 16)
                            | ((unsigned long long)o2 << 32) | ((unsigned long long)o3 << 48);
    *(unsigned long long*)(dst + i) = pack;
  } else {
    for (int k = i; k < n; k++) dst[k] = f2bf(src[k]);
  }
}

// ---------------- grid barrier (agent scope) ----------------
static __device__ __forceinline__ void grid_barrier(unsigned* ctr, unsigned target) {
  __syncthreads();   // all WG threads drained (compiler waits vmcnt before s_barrier)
  if (threadIdx.x == 0) {
    __builtin_amdgcn_fence(__ATOMIC_RELEASE, "agent");   // wbl2: make stores visible
    __hip_atomic_fetch_add(ctr, 1u, __ATOMIC_RELAXED, __HIP_MEMORY_SCOPE_AGENT);
    while (__hip_atomic_load(ctr, __ATOMIC_RELAXED, __HIP_MEMORY_SCOPE_AGENT) < target) {
      __builtin_amdgcn_s_sleep(2);
    }
    __builtin_amdgcn_fence(__ATOMIC_ACQUIRE, "agent");   // inv: see others' stores
  }
  __syncthreads();
}

// ---------------- persistent recurrent layer ----------------
// KX: input width (256 for layer1, 512 for layer2). LAYER1: write h1seq bf16,
// else write f32 output (+ last step tail).
template <int KX, bool LAYER1>
__global__ __launch_bounds__(THREADS, 1)
void rnn_layer_kernel(const unsigned short* __restrict__ Whb,   // [3H][H] bf16
                      const unsigned short* __restrict__ Wxb,   // [3H][KX] bf16
                      const float* __restrict__ bh,             // [3H]
                      const float* __restrict__ bx,             // [3H]
                      const float* __restrict__ beta,           // [1]
                      const unsigned short* __restrict__ xin,   // [S][B][KX] bf16
                      unsigned short* __restrict__ hbuf0,       // [B][H] bf16 (h)
                      unsigned short* __restrict__ hbuf1,       // [B][H] bf16 (half)
                      unsigned short* __restrict__ h1seq,       // [S][B][H] bf16 or null
                      float* __restrict__ outf,                 // [S][B][H] f32 or null
                      float* __restrict__ outlast,              // [B][H] f32 or null
                      unsigned* __restrict__ bar) {
  __shared__ unsigned short lds_wh[48 * HID];
  __shared__ unsigned short lds_wx[48 * KX];

  const int w    = blockIdx.x;      // 0..31, owns hidden cols [w*16, w*16+16)
  const int tid  = threadIdx.x;
  const int lane = tid & 63;
  const int waveM = tid >> 6;       // wave handles batch rows [waveM*32, +32)

  // ---- load weight slices into LDS, XOR-swizzled on 16B chunks ----
  // local row r = g*16 + c  ->  global weight row = g*HID + w*HC + c
  for (int idx = tid; idx < 48 * HID / 8; idx += THREADS) {
    int r = (idx * 8) / HID, k0 = (idx * 8) % HID;
    int grow = (r / 16) * HID + w * HC + (r % 16);
    short8 v = *(const short8*)(Whb + grow * HID + k0);
    int didx = (r * HID + k0) ^ ((r & 7) << 3);
    *(short8*)(&lds_wh[didx]) = v;
  }
  for (int idx = tid; idx < 48 * KX / 8; idx += THREADS) {
    int r = (idx * 8) / KX, k0 = (idx * 8) % KX;
    int grow = (r / 16) * HID + w * HC + (r % 16);
    short8 v = *(const short8*)(Wxb + grow * KX + k0);
    int didx = (r * KX + k0) ^ ((r & 7) << 3);
    *(short8*)(&lds_wx[didx]) = v;
  }

  // ---- per-lane constants ----
  const int j = w * HC + (lane & 15);         // owned hidden col (C frag: col=lane&15)
  const float bxr = bx[j], bxi = bx[HID + j], bxn = bx[2 * HID + j];
  const float bhr = bh[j], bhi = bh[HID + j], bhn = bh[2 * HID + j];
  const float sb  = sigmoidf_(beta[0]);
  const float sa  = 0.26894142136999512f;     // sigmoid(-1)
  const float a20 = 1.f - sa;
  const float b21 = 1.f / (2.f * sb);
  const float b20 = 1.f - b21 - sa * sb;

  const int arow0 = waveM * 32 + (lane & 15); // A frag row (mf adds 16)
  const int akoff = (lane >> 4) * 8;          // A frag k sub-offset
  const int crow0 = waveM * 32 + ((lane >> 4) << 2); // C frag row base (+mf*16+r)
  const int swz   = (lane & 7) << 3;          // B frag LDS swizzle (row&7)

  float hown[2][4], f1v[2][4], halfv[2][4];
  float gxr[2][4], gxi[2][4], gxn[2][4];
#pragma unroll
  for (int mf = 0; mf < 2; mf++)
#pragma unroll
    for (int r = 0; r < 4; r++) hown[mf][r] = 0.f;

  __syncthreads();
  unsigned wall = 0;
  const f32x4 zero4 = {0.f, 0.f, 0.f, 0.f};

  for (int t = 0; t < S_LEN; ++t) {
    // ================= wall A: gx = x@Wx^T (kept), gh1 = h@Wh^T =================
    f32x4 gx[2][3], gh[2][3];
#pragma unroll
    for (int mf = 0; mf < 2; mf++)
#pragma unroll
      for (int g = 0; g < 3; g++) { gx[mf][g] = zero4; gh[mf][g] = zero4; }

    const unsigned short* xt = xin + (size_t)t * BATCH * KX;
#pragma unroll 4
    for (int kk = 0; kk < KX / 32; ++kk) {
      int k0 = kk * 32 + akoff;
      short8 a0 = *(const short8*)(xt + arow0 * KX + k0);
      short8 a1 = *(const short8*)(xt + (arow0 + 16) * KX + k0);
#pragma unroll
      for (int g = 0; g < 3; ++g) {
        short8 b = *(const short8*)(&lds_wx[((g * 16 + (lane & 15)) * KX + k0) ^ swz]);
        gx[0][g] = mfma16(a0, b, gx[0][g]);
        gx[1][g] = mfma16(a1, b, gx[1][g]);
      }
    }
#pragma unroll 4
    for (int kk = 0; kk < HID / 32; ++kk) {
      int k0 = kk * 32 + akoff;
      short8 a0 = *(const short8*)(hbuf0 + arow0 * HID + k0);
      short8 a1 = *(const short8*)(hbuf0 + (arow0 + 16) * HID + k0);
#pragma unroll
      for (int g = 0; g < 3; ++g) {
        short8 b = *(const short8*)(&lds_wh[((g * 16 + (lane & 15)) * HID + k0) ^ swz]);
        gh[0][g] = mfma16(a0, b, gh[0][g]);
        gh[1][g] = mfma16(a1, b, gh[1][g]);
      }
    }
#pragma unroll
    for (int mf = 0; mf < 2; ++mf)
#pragma unroll
      for (int r = 0; r < 4; ++r) {
        float xr = gx[mf][0][r] + bxr, xi = gx[mf][1][r] + bxi, xn = gx[mf][2][r] + bxn;
        gxr[mf][r] = xr; gxi[mf][r] = xi; gxn[mf][r] = xn;
        float hr = gh[mf][0][r] + bhr, hi = gh[mf][1][r] + bhi, hn_ = gh[mf][2][r] + bhn;
        float rg = sigmoidf_(xr + hr);
        float ig = sigmoidf_(xi + hi);
        float ng = tanhf_(xn + rg * hn_);
        float h0 = hown[mf][r];
        float f1 = (1.f - ig) * (ng - h0);
        float hf = h0 + sb * f1;
        f1v[mf][r] = f1; halfv[mf][r] = hf;
        hbuf1[(crow0 + mf * 16 + r) * HID + j] = f2bf(hf);
      }
    ++wall; grid_barrier(bar, NWG * wall);

    // ================= wall B: gh2 = half@Wh^T, RK2 blend =================
    f32x4 gh2[2][3];
#pragma unroll
    for (int mf = 0; mf < 2; mf++)
#pragma unroll
      for (int g = 0; g < 3; g++) gh2[mf][g] = zero4;
#pragma unroll 4
    for (int kk = 0; kk < HID / 32; ++kk) {
      int k0 = kk * 32 + akoff;
      short8 a0 = *(const short8*)(hbuf1 + arow0 * HID + k0);
      short8 a1 = *(const short8*)(hbuf1 + (arow0 + 16) * HID + k0);
#pragma unroll
      for (int g = 0; g < 3; ++g) {
        short8 b = *(const short8*)(&lds_wh[((g * 16 + (lane & 15)) * HID + k0) ^ swz]);
        gh2[0][g] = mfma16(a0, b, gh2[0][g]);
        gh2[1][g] = mfma16(a1, b, gh2[1][g]);
      }
    }
#pragma unroll
    for (int mf = 0; mf < 2; ++mf)
#pragma unroll
      for (int r = 0; r < 4; ++r) {
        float hr = gh2[mf][0][r] + bhr, hi = gh2[mf][1][r] + bhi, hn_ = gh2[mf][2][r] + bhn;
        float rg = sigmoidf_(gxr[mf][r] + hr);
        float ig = sigmoidf_(gxi[mf][r] + hi);
        float ng = tanhf_(gxn[mf][r] + rg * hn_);
        float hf = halfv[mf][r];
        float f2 = (1.f - ig) * (ng - hf);
        float hnew = a20 * hown[mf][r] + b20 * f1v[mf][r] + sa * hf + b21 * f2;
        hown[mf][r] = hnew;
        int brow = crow0 + mf * 16 + r;
        unsigned short hb = f2bf(hnew);
        hbuf0[brow * HID + j] = hb;
        if (LAYER1) {
          h1seq[(size_t)t * BATCH * HID + brow * HID + j] = hb;
        } else {
          outf[(size_t)t * BATCH * HID + brow * HID + j] = hnew;
          if (t == S_LEN - 1) outlast[brow * HID + j] = hnew;
        }
      }
    ++wall; grid_barrier(bar, NWG * wall);
  }
}

extern "C" void kernel_launch(void* const* d_in, const int* in_sizes, int n_in,
                              void* d_out, int out_size, void* d_ws, size_t ws_size,
                              hipStream_t stream) {
  const float* x     = (const float*)d_in[0];
  const float* Wx0   = (const float*)d_in[1];
  const float* bx0   = (const float*)d_in[2];
  const float* Wh0   = (const float*)d_in[3];
  const float* bh0   = (const float*)d_in[4];
  const float* beta0 = (const float*)d_in[5];
  const float* Wx1   = (const float*)d_in[6];
  const float* bx1   = (const float*)d_in[7];
  const float* Wh1   = (const float*)d_in[8];
  const float* bh1   = (const float*)d_in[9];
  const float* beta1 = (const float*)d_in[10];
  float* out = (float*)d_out;

  // ---- workspace layout ----
  uint8_t* ws = (uint8_t*)d_ws;
  unsigned* bar1 = (unsigned*)(ws + 0);
  unsigned* bar2 = (unsigned*)(ws + 128);
  size_t off = 256;
  unsigned short* hb0_1 = (unsigned short*)(ws + off); off += (size_t)BATCH * HID * 2;
  unsigned short* hb1_1 = (unsigned short*)(ws + off); off += (size_t)BATCH * HID * 2;
  unsigned short* hb0_2 = (unsigned short*)(ws + off); off += (size_t)BATCH * HID * 2;
  unsigned short* hb1_2 = (unsigned short*)(ws + off); off += (size_t)BATCH * HID * 2;
  size_t zero_bytes = off;                       // bars + all h ping-pong buffers
  unsigned short* Wx0b = (unsigned short*)(ws + off); off += (size_t)3 * HID * 256 * 2;
  unsigned short* Wh0b = (unsigned short*)(ws + off); off += (size_t)3 * HID * HID * 2;
  unsigned short* Wx1b = (unsigned short*)(ws + off); off += (size_t)3 * HID * HID * 2;
  unsigned short* Wh1b = (unsigned short*)(ws + off); off += (size_t)3 * HID * HID * 2;
  unsigned short* xb   = (unsigned short*)(ws + off); off += (size_t)S_LEN * BATCH * 256 * 2;
  unsigned short* h1sq = (unsigned short*)(ws + off); off += (size_t)S_LEN * BATCH * HID * 2;
  // total ~102 MB

  hipMemsetAsync(ws, 0, zero_bytes, stream);     // barrier ctrs + h0 = 0

  // ---- f32 -> bf16 conversions ----
  auto cvt = [&](const float* s, unsigned short* d, int n) {
    int blocks = (n / 4 + THREADS - 1) / THREADS;
    cvt_bf16_kernel<<<blocks, THREADS, 0, stream>>>(s, d, n);
  };
  cvt(Wx0, Wx0b, 3 * HID * 256);
  cvt(Wh0, Wh0b, 3 * HID * HID);
  cvt(Wx1, Wx1b, 3 * HID * HID);
  cvt(Wh1, Wh1b, 3 * HID * HID);
  cvt(x,   xb,   S_LEN * BATCH * 256);

  // ---- layer 1 (writes h1 sequence bf16) ----
  rnn_layer_kernel<256, true><<<NWG, THREADS, 0, stream>>>(
      Wh0b, Wx0b, bh0, bx0, beta0, xb, hb0_1, hb1_1, h1sq, nullptr, nullptr, bar1);
  // ---- layer 2 (writes f32 output + last-step tail) ----
  rnn_layer_kernel<HID, false><<<NWG, THREADS, 0, stream>>>(
      Wh1b, Wx1b, bh1, bx1, beta1, h1sq, hb0_2, hb1_2, nullptr, out,
      out + (size_t)S_LEN * BATCH * HID, bar2);
}

// Round 3
// 15666.628 us; speedup vs baseline: 1.4574x; 1.4574x over previous
//
#include <hip/hip_runtime.h>
#include <hip/hip_bf16.h>
#include <stdint.h>

// SSR-GRU (RK2 blend), 2 layers fused + pipelined. S=512 B=128 I=256 H=512.
// 256 persistent WGs = 4 batch-quarter domains x (32 hidden-split WGs x 2 layers).
// Domains are fully independent (batch rows don't couple): private barrier each.
// Each WG: M=32 batch rows, 16 hidden cols (48 gh cols), Wh/Wx slices LDS-resident.
// Coherence: normal loads/stores + R1-PROVEN fence barrier (release wbl2 /
// acquire inv in thread0 around a per-domain atomic counter).

#define S_LEN 512
#define BATCH 128
#define HID   512
#define NB    4              // batch quarters (32 rows each)
#define NH    32             // hidden-split WGs per layer per domain
#define DOMW  (2 * NH)       // WGs per barrier domain (both layers)
#define THREADS 256

typedef __attribute__((ext_vector_type(8))) short short8;
typedef __attribute__((ext_vector_type(4))) float f32x4;

static __device__ __forceinline__ f32x4 mfma16(short8 a, short8 b, f32x4 c) {
  return __builtin_amdgcn_mfma_f32_16x16x32_bf16(a, b, c, 0, 0, 0);
}

static __device__ __forceinline__ unsigned short f2bf(float f) {
  union { float f; unsigned u; } v; v.f = f;
  unsigned r = (v.u + 0x7fffu + ((v.u >> 16) & 1u)) >> 16;
  return (unsigned short)r;
}

static __device__ __forceinline__ float sigmoidf_(float x) {
  x = fminf(fmaxf(x, -30.f), 30.f);
  return 1.0f / (1.0f + __expf(-x));
}
static __device__ __forceinline__ float tanhf_(float x) {
  x = fminf(fmaxf(x, -15.f), 15.f);
  float e = __expf(2.f * x);
  return (e - 1.f) / (e + 1.f);
}

// ---------------- f32 -> bf16 conversion ----------------
__global__ void cvt_bf16_kernel(const float* __restrict__ src,
                                unsigned short* __restrict__ dst, int n) {
  int i = (blockIdx.x * blockDim.x + threadIdx.x) * 4;
  if (i + 3 < n) {
    float4 v = *(const float4*)(src + i);
    unsigned short o0 = f2bf(v.x), o1 = f2bf(v.y), o2 = f2bf(v.z), o3 = f2bf(v.w);
    unsigned long long pack = (unsigned long long)o0 | ((unsigned long long)o1 << 16)
                            | ((unsigned long long)o2 << 32) | ((unsigned long long)o3 << 48);
    *(unsigned long long*)(dst + i) = pack;
  } else {
    for (int k = i; k < n; k++) dst[k] = f2bf(src[k]);
  }
}

// ------------- per-domain grid barrier (R1-proven fence protocol) -------------
static __device__ __forceinline__ void grid_barrier(unsigned* ctr, unsigned target) {
  __syncthreads();   // every wave: s_waitcnt vmcnt(0) before s_barrier
  if (threadIdx.x == 0) {
    __builtin_amdgcn_fence(__ATOMIC_RELEASE, "agent");   // wbl2: flush WG's dirty L2
    __hip_atomic_fetch_add(ctr, 1u, __ATOMIC_RELAXED, __HIP_MEMORY_SCOPE_AGENT);
    while (__hip_atomic_load(ctr, __ATOMIC_RELAXED, __HIP_MEMORY_SCOPE_AGENT) < target) {
      __builtin_amdgcn_s_sleep(1);
    }
    __builtin_amdgcn_fence(__ATOMIC_ACQUIRE, "agent");   // inv: drop stale L1/L2
  }
  __syncthreads();
}

// ---- one GEMM pass: acc[mf][g] += A[rows 0..31 of slice, K] x B_lds[48,K]^T ----
template <int K>
static __device__ __forceinline__ void gemm_pass(const unsigned short* __restrict__ A,
                                                 const unsigned short* __restrict__ ldsB,
                                                 int arow0, int akoff, int c15, int swz,
                                                 f32x4 acc[2][3]) {
#pragma unroll 4
  for (int kk = 0; kk < K / 32; ++kk) {
    int k0 = kk * 32 + akoff;
    short8 a0 = *(const short8*)(A + (size_t)arow0 * K + k0);
    short8 a1 = *(const short8*)(A + (size_t)(arow0 + 16) * K + k0);
#pragma unroll
    for (int g = 0; g < 3; ++g) {
      short8 b = *(const short8*)(&ldsB[((g * 16 + c15) * K + k0) ^ swz]);
      acc[0][g] = mfma16(a0, b, acc[0][g]);
      acc[1][g] = mfma16(a1, b, acc[1][g]);
    }
  }
}

// ---------------- fused persistent 2-layer recurrent kernel ----------------
__global__ __launch_bounds__(THREADS, 1)
void rnn_fused_kernel(const unsigned short* __restrict__ Wh0b, const unsigned short* __restrict__ Wx0b,
                      const float* __restrict__ bh0, const float* __restrict__ bx0,
                      const float* __restrict__ beta0,
                      const unsigned short* __restrict__ Wh1b, const unsigned short* __restrict__ Wx1b,
                      const float* __restrict__ bh1, const float* __restrict__ bx1,
                      const float* __restrict__ beta1,
                      const unsigned short* __restrict__ xb,     // [S][B][256] bf16
                      unsigned short* __restrict__ h1seq,        // [S][B][H] bf16 handoff
                      unsigned short* __restrict__ hb0A, unsigned short* __restrict__ hb1A,
                      unsigned short* __restrict__ hb0B, unsigned short* __restrict__ hb1B,
                      float* __restrict__ outf, float* __restrict__ outlast,
                      unsigned* __restrict__ bars) {
  __shared__ unsigned short lds_wh[48 * HID];
  __shared__ unsigned short lds_wx[48 * HID];   // layer1 uses only 48*256

  // block decode: domain d (batch quarter), layer L, hidden-split hs
  const int d   = blockIdx.x & (NB - 1);
  const int rem = blockIdx.x >> 2;
  const int L   = rem >> 5;           // 0 = layer1, 1 = layer2
  const int hs  = rem & (NH - 1);     // owns hidden cols [hs*16, hs*16+16)
  const int rb  = d * 32;             // batch row base of this quarter

  const int tid  = threadIdx.x;
  const int lane = tid & 63;
  const int waveM = tid >> 6;

  const unsigned short* Whb = L ? Wh1b : Wh0b;
  const unsigned short* Wxb = L ? Wx1b : Wx0b;
  const float* bh = L ? bh1 : bh0;
  const float* bx = L ? bx1 : bx0;
  const float betav = L ? beta1[0] : beta0[0];
  const int KX = L ? HID : 256;
  unsigned short* hb0 = L ? hb0B : hb0A;
  unsigned short* hb1 = L ? hb1B : hb1A;
  unsigned* bar = bars + d * 32;      // 128B-separated per-domain counter

  const int j0 = hs * 16;

  // ---- load weight slices into LDS, XOR-swizzled on 16B chunks ----
  for (int idx = tid; idx < 48 * HID / 8; idx += THREADS) {
    int r = (idx * 8) / HID, k0 = (idx * 8) % HID;
    int grow = (r / 16) * HID + j0 + (r % 16);
    short8 v = *(const short8*)(Whb + (size_t)grow * HID + k0);
    int didx = (r * HID + k0) ^ ((r & 7) << 3);
    *(short8*)(&lds_wh[didx]) = v;
  }
  for (int idx = tid; idx < 48 * KX / 8; idx += THREADS) {
    int r = (idx * 8) / KX, k0 = (idx * 8) % KX;
    int grow = (r / 16) * HID + j0 + (r % 16);
    short8 v = *(const short8*)(Wxb + (size_t)grow * KX + k0);
    int didx = (r * KX + k0) ^ ((r & 7) << 3);
    *(short8*)(&lds_wx[didx]) = v;
  }

  // ---- per-lane constants ----
  const int c15 = lane & 15;
  const int j = j0 + c15;                     // owned hidden col
  const float bxr = bx[j], bxi = bx[HID + j], bxn = bx[2 * HID + j];
  const float bhr = bh[j], bhi = bh[HID + j], bhn = bh[2 * HID + j];
  const float sb  = sigmoidf_(betav);
  const float sa  = 0.26894142136999512f;     // sigmoid(-1)
  const float a20 = 1.f - sa;
  const float b21 = 1.f / (2.f * sb);
  const float b20 = 1.f - b21 - sa * sb;

  const int arow0 = rb + c15;                        // A frag row (mf adds 16)
  const int akoff = (lane >> 4) * 8;                 // A frag k sub-offset
  const int crow0 = rb + ((lane >> 4) << 2);         // C frag row base (+mf*16+r)
  const int swz   = (lane & 7) << 3;                 // B frag LDS swizzle

  float hown[2][4], f1v[2][4], halfv[2][4];
  float gxr[2][4], gxi[2][4], gxn[2][4];
#pragma unroll
  for (int mf = 0; mf < 2; mf++)
#pragma unroll
    for (int r = 0; r < 4; r++) hown[mf][r] = 0.f;

  const f32x4 zero4 = {0.f, 0.f, 0.f, 0.f};
  unsigned wall = 0;

  for (int W = 0; W < 2 * S_LEN + 2; ++W) {
    const int t = (W >> 1) - L;               // this layer's step (pipelined)
    const int phase = W & 1;
    if (t >= 0 && t < S_LEN) {
      if (phase == 0) {
        // ======= phase A: gx (x2h) + gh1 = h@Wh^T; f1, half =======
        f32x4 gx[2][3], gh[2][3];
#pragma unroll
        for (int mf = 0; mf < 2; mf++)
#pragma unroll
          for (int g = 0; g < 3; g++) { gx[mf][g] = zero4; gh[mf][g] = zero4; }
        if (L == 0)
          gemm_pass<256>(xb + (size_t)t * BATCH * 256, lds_wx, arow0, akoff, c15, swz, gx);
        else
          gemm_pass<HID>(h1seq + (size_t)t * BATCH * HID, lds_wx, arow0, akoff, c15, swz, gx);
        gemm_pass<HID>(hb0, lds_wh, arow0, akoff, c15, swz, gh);
#pragma unroll
        for (int mf = 0; mf < 2; ++mf)
#pragma unroll
          for (int r = 0; r < 4; ++r) {
            float xr = gx[mf][0][r] + bxr, xi = gx[mf][1][r] + bxi, xn = gx[mf][2][r] + bxn;
            gxr[mf][r] = xr; gxi[mf][r] = xi; gxn[mf][r] = xn;
            float hr = gh[mf][0][r] + bhr, hi = gh[mf][1][r] + bhi, hn_ = gh[mf][2][r] + bhn;
            float rg = sigmoidf_(xr + hr);
            float ig = sigmoidf_(xi + hi);
            float ng = tanhf_(xn + rg * hn_);
            float h0 = hown[mf][r];
            float f1 = (1.f - ig) * (ng - h0);
            float hf = h0 + sb * f1;
            f1v[mf][r] = f1; halfv[mf][r] = hf;
            hb1[(size_t)(crow0 + mf * 16 + r) * HID + j] = f2bf(hf);
          }
      } else {
        // ======= phase B: gh2 = half@Wh^T; RK2 blend =======
        f32x4 gh2[2][3];
#pragma unroll
        for (int mf = 0; mf < 2; mf++)
#pragma unroll
          for (int g = 0; g < 3; g++) gh2[mf][g] = zero4;
        gemm_pass<HID>(hb1, lds_wh, arow0, akoff, c15, swz, gh2);
#pragma unroll
        for (int mf = 0; mf < 2; ++mf)
#pragma unroll
          for (int r = 0; r < 4; ++r) {
            float hr = gh2[mf][0][r] + bhr, hi = gh2[mf][1][r] + bhi, hn_ = gh2[mf][2][r] + bhn;
            float rg = sigmoidf_(gxr[mf][r] + hr);
            float ig = sigmoidf_(gxi[mf][r] + hi);
            float ng = tanhf_(gxn[mf][r] + rg * hn_);
            float hf = halfv[mf][r];
            float f2 = (1.f - ig) * (ng - hf);
            float hnew = a20 * hown[mf][r] + b20 * f1v[mf][r] + sa * hf + b21 * f2;
            hown[mf][r] = hnew;
            int brow = crow0 + mf * 16 + r;
            unsigned short hb = f2bf(hnew);
            hb0[(size_t)brow * HID + j] = hb;
            if (L == 0) {
              h1seq[(size_t)t * BATCH * HID + (size_t)brow * HID + j] = hb;
            } else {
              outf[(size_t)t * BATCH * HID + (size_t)brow * HID + j] = hnew;
              if (t == S_LEN - 1) outlast[(size_t)brow * HID + j] = hnew;
            }
          }
      }
    }
    ++wall;
    grid_barrier(bar, DOMW * wall);
  }
}

extern "C" void kernel_launch(void* const* d_in, const int* in_sizes, int n_in,
                              void* d_out, int out_size, void* d_ws, size_t ws_size,
                              hipStream_t stream) {
  const float* x     = (const float*)d_in[0];
  const float* Wx0   = (const float*)d_in[1];
  const float* bx0   = (const float*)d_in[2];
  const float* Wh0   = (const float*)d_in[3];
  const float* bh0   = (const float*)d_in[4];
  const float* beta0 = (const float*)d_in[5];
  const float* Wx1   = (const float*)d_in[6];
  const float* bx1   = (const float*)d_in[7];
  const float* Wh1   = (const float*)d_in[8];
  const float* bh1   = (const float*)d_in[9];
  const float* beta1 = (const float*)d_in[10];
  float* out = (float*)d_out;

  // ---- workspace layout ----
  uint8_t* ws = (uint8_t*)d_ws;
  unsigned* bars = (unsigned*)ws;                // 4 domains x 128B
  size_t off = 512;
  unsigned short* hb0_1 = (unsigned short*)(ws + off); off += (size_t)BATCH * HID * 2;
  unsigned short* hb1_1 = (unsigned short*)(ws + off); off += (size_t)BATCH * HID * 2;
  unsigned short* hb0_2 = (unsigned short*)(ws + off); off += (size_t)BATCH * HID * 2;
  unsigned short* hb1_2 = (unsigned short*)(ws + off); off += (size_t)BATCH * HID * 2;
  size_t zero_bytes = off;                       // bars + all h ping-pong buffers
  unsigned short* Wx0b = (unsigned short*)(ws + off); off += (size_t)3 * HID * 256 * 2;
  unsigned short* Wh0b = (unsigned short*)(ws + off); off += (size_t)3 * HID * HID * 2;
  unsigned short* Wx1b = (unsigned short*)(ws + off); off += (size_t)3 * HID * HID * 2;
  unsigned short* Wh1b = (unsigned short*)(ws + off); off += (size_t)3 * HID * HID * 2;
  unsigned short* xb   = (unsigned short*)(ws + off); off += (size_t)S_LEN * BATCH * 256 * 2;
  unsigned short* h1sq = (unsigned short*)(ws + off); off += (size_t)S_LEN * BATCH * HID * 2;

  hipMemsetAsync(ws, 0, zero_bytes, stream);     // barrier ctrs + h0 = 0

  auto cvt = [&](const float* s, unsigned short* d, int n) {
    int blocks = (n / 4 + THREADS - 1) / THREADS;
    cvt_bf16_kernel<<<blocks, THREADS, 0, stream>>>(s, d, n);
  };
  cvt(Wx0, Wx0b, 3 * HID * 256);
  cvt(Wh0, Wh0b, 3 * HID * HID);
  cvt(Wx1, Wx1b, 3 * HID * HID);
  cvt(Wh1, Wh1b, 3 * HID * HID);
  cvt(x,   xb,   S_LEN * BATCH * 256);

  rnn_fused_kernel<<<NB * DOMW, THREADS, 0, stream>>>(
      Wh0b, Wx0b, bh0, bx0, beta0,
      Wh1b, Wx1b, bh1, bx1, beta1,
      xb, h1sq, hb0_1, hb1_1, hb0_2, hb1_2,
      out, out + (size_t)S_LEN * BATCH * HID, bars);
}